// Round 2
// baseline (71620.844 us; speedup 1.0000x reference)
//
#include <hip/hip_runtime.h>
#include <cfloat>
#include <cstdint>

#define N_PTS 16384
#define KNN_K 16
#define KNN_TILE 512

// ---------------------------------------------------------------------------
// KNN: one wave per query point, per-lane top-16 (fp64 exact) + wave merge.
// Block = 256 threads = 4 waves = 4 queries. Grid = 4096.
// ---------------------------------------------------------------------------
__global__ __launch_bounds__(256) void knn_kernel(const float* __restrict__ pts,
                                                  int* __restrict__ knn_out) {
    __shared__ float sx[KNN_TILE], sy[KNN_TILE], sz[KNN_TILE];
    const int wave = threadIdx.x >> 6;
    const int lane = threadIdx.x & 63;
    const int qi = blockIdx.x * 4 + wave;
    const double qxd = (double)pts[qi * 3 + 0];
    const double qyd = (double)pts[qi * 3 + 1];
    const double qzd = (double)pts[qi * 3 + 2];

    double ld[16];
    int li[16];
#pragma unroll
    for (int s = 0; s < 16; ++s) { ld[s] = DBL_MAX; li[s] = 0x7fffffff; }
    double md = DBL_MAX; int mj = 0x7fffffff; int mslot = 0;

    for (int t0 = 0; t0 < N_PTS; t0 += KNN_TILE) {
        __syncthreads();
        for (int t = threadIdx.x; t < KNN_TILE; t += 256) {
            sx[t] = pts[(t0 + t) * 3 + 0];
            sy[t] = pts[(t0 + t) * 3 + 1];
            sz[t] = pts[(t0 + t) * 3 + 2];
        }
        __syncthreads();
#pragma unroll
        for (int m = 0; m < KNN_TILE / 64; ++m) {
            const int c = lane + m * 64;
            const int j = t0 + c;
            if (j == qi) continue;  // diagonal excluded (d=inf in reference)
            double dx = qxd - (double)sx[c];
            double dy = qyd - (double)sy[c];
            double dz = qzd - (double)sz[c];
            double dd = dx * dx + dy * dy + dz * dz;
            // accept if (dd,j) lex-less than current max (md,mj)
            if (dd < md || (dd == md && j < mj)) {
#pragma unroll
                for (int s = 0; s < 16; ++s)
                    if (s == mslot) { ld[s] = dd; li[s] = j; }
                // rescan for new max
                md = -1.0; mj = -1; mslot = 0;
#pragma unroll
                for (int s = 0; s < 16; ++s) {
                    bool g = (ld[s] > md) || (ld[s] == md && li[s] > mj);
                    if (g) { md = ld[s]; mj = li[s]; mslot = s; }
                }
            }
        }
    }

    // Wave merge: 16 rounds of extract-min over 64 lanes' local lists.
    const int out_base = qi * KNN_K;
    for (int r = 0; r < KNN_K; ++r) {
        double cd = DBL_MAX; int cj = 0x7fffffff; int cs = 0;
#pragma unroll
        for (int s = 0; s < 16; ++s) {
            bool l = (ld[s] < cd) || (ld[s] == cd && li[s] < cj);
            if (l) { cd = ld[s]; cj = li[s]; cs = s; }
        }
        double wd = cd; int wj = cj;
        for (int off = 32; off; off >>= 1) {
            double od = __shfl_xor(wd, off);
            int oj = __shfl_xor(wj, off);
            if (od < wd || (od == wd && oj < wj)) { wd = od; wj = oj; }
        }
        if (cd == wd && cj == wj) {  // unique winner lane consumes its slot
#pragma unroll
            for (int s = 0; s < 16; ++s)
                if (s == cs) { ld[s] = DBL_MAX; li[s] = 0x7fffffff; }
        }
        if (lane == 0) knn_out[out_base + r] = wj;
    }
}

// ---------------------------------------------------------------------------
// EdgeConv MLP + maxpool: one wave per point (lane = channel 0..63).
// ---------------------------------------------------------------------------
__global__ __launch_bounds__(256) void edgeconv_kernel(
    const float* __restrict__ pts, const int* __restrict__ knn,
    const float* __restrict__ ew1, const float* __restrict__ eb1,
    const float* __restrict__ ew2, const float* __restrict__ eb2,
    float* __restrict__ feats) {
    __shared__ float w1[6 * 64], b1v[64], w2[64 * 64], b2v[64];
    for (int t = threadIdx.x; t < 6 * 64; t += 256) w1[t] = ew1[t];
    for (int t = threadIdx.x; t < 64; t += 256) { b1v[t] = eb1[t]; b2v[t] = eb2[t]; }
    for (int t = threadIdx.x; t < 64 * 64; t += 256) w2[t] = ew2[t];
    __syncthreads();

    const int wave = threadIdx.x >> 6, lane = threadIdx.x & 63;
    const int p = blockIdx.x * 4 + wave;
    const float xi = pts[p * 3], yi = pts[p * 3 + 1], zi = pts[p * 3 + 2];
    float acc = -FLT_MAX;
    for (int k = 0; k < KNN_K; ++k) {
        const int j = knn[p * 16 + k];
        const float xj = pts[j * 3], yj = pts[j * 3 + 1], zj = pts[j * 3 + 2];
        const float f0 = xi, f1 = yi, f2 = zi;
        const float f3 = xj - xi, f4 = yj - yi, f5 = zj - zi;
        float h1 = b1v[lane];
        h1 = fmaf(f0, w1[0 * 64 + lane], h1);
        h1 = fmaf(f1, w1[1 * 64 + lane], h1);
        h1 = fmaf(f2, w1[2 * 64 + lane], h1);
        h1 = fmaf(f3, w1[3 * 64 + lane], h1);
        h1 = fmaf(f4, w1[4 * 64 + lane], h1);
        h1 = fmaf(f5, w1[5 * 64 + lane], h1);
        h1 = fmaxf(h1, 0.0f);
        float h2 = b2v[lane];
        for (int d = 0; d < 64; ++d)
            h2 = fmaf(__shfl(h1, d), w2[d * 64 + lane], h2);
        acc = fmaxf(acc, h2);
    }
    feats[p * 64 + lane] = acc;
}

// ---------------------------------------------------------------------------
// FPS v2: 256 threads (4 waves), P = n/256 points per thread.
// Fused min-update + local top-2 in certified fp32; per-wave butterfly top-2;
// ONE barrier/iter; all threads redundantly merge 4 LDS slots.
// If global 2nd max is within 1e-5 rel of max (fp32 cannot certify the fp64
// argmax), fall back to exact fp64 re-evaluation of band candidates against
// the full selected history (fi[] in global; __syncthreads orders writes).
// ---------------------------------------------------------------------------
template <int P>
__global__ __launch_bounds__(256, 1) void fps_kernel(const float* __restrict__ pts,
                                                     int n_out,
                                                     int* __restrict__ fi) {
    __shared__ float rm1[2][4];
    __shared__ int rg1[2][4];
    __shared__ float rm2[2][4];
    __shared__ double rd64[4];
    __shared__ int rg64[4];
    const int tid = threadIdx.x;
    const int wave = tid >> 6, lane = tid & 63;

    float px[P], py[P], pz[P], c[P];
#pragma unroll
    for (int q = 0; q < P; ++q) {
        const int g = tid + q * 256;
        px[q] = pts[g * 3 + 0];
        py[q] = pts[g * 3 + 1];
        pz[q] = pts[g * 3 + 2];
        c[q] = FLT_MAX;
    }
    float sx = pts[0], sy = pts[1], sz = pts[2];
    if (tid == 0) fi[0] = 0;

    for (int it = 1; it < n_out; ++it) {
        // fused min-update + per-thread top-2 (lex tie-break: smaller index)
        float m1 = -1.0f, m2 = -1.0f;
        int g1 = 0x7fffffff;
#pragma unroll
        for (int q = 0; q < P; ++q) {
            float dx = px[q] - sx, dy = py[q] - sy, dz = pz[q] - sz;
            float t = fmaf(dx, dx, fmaf(dy, dy, dz * dz));
            float nc = fminf(c[q], t);
            c[q] = nc;
            bool gt = nc > m1;
            m2 = fmaxf(m2, fminf(nc, m1));  // gt: old m1 demoted; else nc vies for 2nd
            m1 = fmaxf(m1, nc);
            g1 = gt ? (tid + q * 256) : g1;
        }
        // wave butterfly top-2 merge (disjoint candidate sets)
        for (int off = 32; off; off >>= 1) {
            float om1 = __shfl_xor(m1, off);
            int og1 = __shfl_xor(g1, off);
            float om2 = __shfl_xor(m2, off);
            bool take = (om1 > m1) || (om1 == m1 && og1 < g1);
            float sml = take ? m1 : om1;
            m2 = fmaxf(fmaxf(m2, om2), sml);
            m1 = take ? om1 : m1;
            g1 = take ? og1 : g1;
        }
        const int par = it & 1;
        if (lane == 0) { rm1[par][wave] = m1; rg1[par][wave] = g1; rm2[par][wave] = m2; }
        __syncthreads();
        float M1 = rm1[par][0], M2 = rm2[par][0];
        int G1 = rg1[par][0];
#pragma unroll
        for (int w = 1; w < 4; ++w) {
            float om1 = rm1[par][w], om2 = rm2[par][w];
            int og1 = rg1[par][w];
            bool take = (om1 > M1) || (om1 == M1 && og1 < G1);
            float sml = take ? M1 : om1;
            M2 = fmaxf(fmaxf(M2, om2), sml);
            M1 = take ? om1 : M1;
            G1 = take ? og1 : G1;
        }
        int winner = G1;
        const float thr = M1 - M1 * 1e-5f;
        if (M2 >= thr) {
            // ---- exact fp64 fallback (rare): re-evaluate band candidates ----
            double bd = -1.0;
            int bg = 0x7fffffff;
            for (int q = 0; q < P; ++q) {
                if (c[q] >= thr) {
                    const double qx = (double)px[q], qy = (double)py[q], qz = (double)pz[q];
                    double d64 = DBL_MAX;
                    for (int i = 0; i < it; ++i) {
                        const int g = fi[i];
                        double dx = qx - (double)pts[g * 3 + 0];
                        double dy = qy - (double)pts[g * 3 + 1];
                        double dz = qz - (double)pts[g * 3 + 2];
                        double dd = dx * dx + dy * dy + dz * dz;
                        d64 = (dd < d64) ? dd : d64;
                    }
                    const int gq = tid + q * 256;
                    if (d64 > bd || (d64 == bd && gq < bg)) { bd = d64; bg = gq; }
                }
            }
            for (int off = 32; off; off >>= 1) {
                double od = __shfl_xor(bd, off);
                int og = __shfl_xor(bg, off);
                if (od > bd || (od == bd && og < bg)) { bd = od; bg = og; }
            }
            if (lane == 0) { rd64[wave] = bd; rg64[wave] = bg; }
            __syncthreads();
            double BD = rd64[0];
            int BG = rg64[0];
#pragma unroll
            for (int w = 1; w < 4; ++w) {
                double od = rd64[w];
                int og = rg64[w];
                if (od > BD || (od == BD && og < BG)) { BD = od; BG = og; }
            }
            winner = BG;
            __syncthreads();
        }
        if (tid == 0) fi[it] = winner;
        winner = __builtin_amdgcn_readfirstlane(winner);
        sx = pts[winner * 3 + 0];
        sy = pts[winner * 3 + 1];
        sz = pts[winner * 3 + 2];
    }
}

// ---------------------------------------------------------------------------
// Gathers: write sampled coords (exact bit copies) + compose original indices.
// ---------------------------------------------------------------------------
__global__ void gather0_kernel(const float* __restrict__ pts,
                               const int* __restrict__ fi0,
                               float* __restrict__ sp0) {
    int t = blockIdx.x * 256 + threadIdx.x;
    if (t >= 4096) return;
    int g = fi0[t];
    sp0[t * 3 + 0] = pts[g * 3 + 0];
    sp0[t * 3 + 1] = pts[g * 3 + 1];
    sp0[t * 3 + 2] = pts[g * 3 + 2];
}

__global__ void gather_next_kernel(const float* __restrict__ pts,
                                   const int* __restrict__ prev_orig,
                                   const int* __restrict__ fi, int S,
                                   float* __restrict__ sp,
                                   int* __restrict__ orig_out) {
    int t = blockIdx.x * 256 + threadIdx.x;
    if (t >= S) return;
    int f = fi[t];            // index into previous sp
    int g = prev_orig[f];     // original point index (== reference's argmin nn)
    orig_out[t] = g;
    sp[t * 3 + 0] = pts[g * 3 + 0];
    sp[t * 3 + 1] = pts[g * 3 + 1];
    sp[t * 3 + 2] = pts[g * 3 + 2];
}

// ---------------------------------------------------------------------------
// Per-scale MLP: lf = relu(sf @ mw1 + mb1) @ mw2 + mb2.
// ---------------------------------------------------------------------------
__global__ __launch_bounds__(256) void mlp_kernel(
    const float* __restrict__ feats, const int* __restrict__ orig,
    const float* __restrict__ mw1, const float* __restrict__ mb1,
    const float* __restrict__ mw2, const float* __restrict__ mb2,
    float* __restrict__ out) {
    __shared__ float sfl[64], h1l[128];
    const int t = threadIdx.x;
    for (int pl = 0; pl < 16; ++pl) {
        const int p = blockIdx.x * 16 + pl;
        const int g = orig[p];
        if (t < 64) sfl[t] = feats[g * 64 + t];
        __syncthreads();
        if (t < 128) {
            float h = mb1[t];
            for (int dd = 0; dd < 64; ++dd)
                h = fmaf(sfl[dd], mw1[dd * 128 + t], h);
            h1l[t] = fmaxf(h, 0.0f);
        }
        __syncthreads();
        float o = mb2[t];
        for (int dd = 0; dd < 128; ++dd)
            o = fmaf(h1l[dd], mw2[dd * 256 + t], o);
        out[p * 256 + t] = o;
        __syncthreads();
    }
}

// ---------------------------------------------------------------------------
extern "C" void kernel_launch(void* const* d_in, const int* in_sizes, int n_in,
                              void* d_out, int out_size, void* d_ws, size_t ws_size,
                              hipStream_t stream) {
    const float* pts = (const float*)d_in[0];
    const float* ew1 = (const float*)d_in[1];
    const float* eb1 = (const float*)d_in[2];
    const float* ew2 = (const float*)d_in[3];
    const float* eb2 = (const float*)d_in[4];
    const float* mw1 = (const float*)d_in[5];  // (3,64,128)
    const float* mb1 = (const float*)d_in[6];  // (3,128)
    const float* mw2 = (const float*)d_in[7];  // (3,128,256)
    const float* mb2 = (const float*)d_in[8];  // (3,256)
    float* out = (float*)d_out;
    char* ws = (char*)d_ws;

    // workspace layout
    int* knn = (int*)(ws + 0);                        // 16384*16*4 = 1 MB
    float* feats = (float*)(ws + 1048576);            // 16384*64*4 = 4 MB
    int* fi0 = (int*)(ws + 5242880);                  // 4096 ints
    int* fi1 = (int*)(ws + 5259264);                  // 1024 ints
    int* fi2 = (int*)(ws + 5263360);                  // 256 ints
    int* orig1 = (int*)(ws + 5264384);                // 1024 ints
    int* orig2 = (int*)(ws + 5268480);                // 256 ints

    // output layout (floats)
    float* sp0 = out + 0;
    float* lf0 = out + 12288;
    float* sp1 = out + 1060864;
    float* lf1 = out + 1063936;
    float* sp2 = out + 1326080;
    float* lf2 = out + 1326848;

    knn_kernel<<<N_PTS / 4, 256, 0, stream>>>(pts, knn);
    edgeconv_kernel<<<N_PTS / 4, 256, 0, stream>>>(pts, knn, ew1, eb1, ew2, eb2, feats);

    // scale 0: FPS over 16384 -> 4096
    fps_kernel<64><<<1, 256, 0, stream>>>(pts, 4096, fi0);
    gather0_kernel<<<16, 256, 0, stream>>>(pts, fi0, sp0);
    mlp_kernel<<<4096 / 16, 256, 0, stream>>>(feats, fi0, mw1 + 0 * 8192, mb1 + 0 * 128,
                                              mw2 + 0 * 32768, mb2 + 0 * 256, lf0);

    // scale 1: FPS over sp0 (4096) -> 1024
    fps_kernel<16><<<1, 256, 0, stream>>>(sp0, 1024, fi1);
    gather_next_kernel<<<4, 256, 0, stream>>>(pts, fi0, fi1, 1024, sp1, orig1);
    mlp_kernel<<<1024 / 16, 256, 0, stream>>>(feats, orig1, mw1 + 1 * 8192, mb1 + 1 * 128,
                                              mw2 + 1 * 32768, mb2 + 1 * 256, lf1);

    // scale 2: FPS over sp1 (1024) -> 256
    fps_kernel<4><<<1, 256, 0, stream>>>(sp1, 256, fi2);
    gather_next_kernel<<<1, 256, 0, stream>>>(pts, orig1, fi2, 256, sp2, orig2);
    mlp_kernel<<<256 / 16, 256, 0, stream>>>(feats, orig2, mw1 + 2 * 8192, mb1 + 2 * 128,
                                             mw2 + 2 * 32768, mb2 + 2 * 256, lf2);
}

// Round 3
// 12875.769 us; speedup vs baseline: 5.5625x; 5.5625x over previous
//
#include <hip/hip_runtime.h>
#include <cfloat>
#include <cstdint>

#define N_PTS 16384
#define KNN_K 16
#define KNN_TILE 512
#define FPS_T 512
#define CERT_EPS 3e-6f

// ---------------------------------------------------------------------------
// KNN: one wave per query point, per-lane top-16 (fp64 exact) + wave merge.
// ---------------------------------------------------------------------------
__global__ __launch_bounds__(256) void knn_kernel(const float* __restrict__ pts,
                                                  int* __restrict__ knn_out) {
    __shared__ float sx[KNN_TILE], sy[KNN_TILE], sz[KNN_TILE];
    const int wave = threadIdx.x >> 6;
    const int lane = threadIdx.x & 63;
    const int qi = blockIdx.x * 4 + wave;
    const double qxd = (double)pts[qi * 3 + 0];
    const double qyd = (double)pts[qi * 3 + 1];
    const double qzd = (double)pts[qi * 3 + 2];

    double ld[16];
    int li[16];
#pragma unroll
    for (int s = 0; s < 16; ++s) { ld[s] = DBL_MAX; li[s] = 0x7fffffff; }
    double md = DBL_MAX; int mj = 0x7fffffff; int mslot = 0;

    for (int t0 = 0; t0 < N_PTS; t0 += KNN_TILE) {
        __syncthreads();
        for (int t = threadIdx.x; t < KNN_TILE; t += 256) {
            sx[t] = pts[(t0 + t) * 3 + 0];
            sy[t] = pts[(t0 + t) * 3 + 1];
            sz[t] = pts[(t0 + t) * 3 + 2];
        }
        __syncthreads();
#pragma unroll
        for (int m = 0; m < KNN_TILE / 64; ++m) {
            const int c = lane + m * 64;
            const int j = t0 + c;
            if (j == qi) continue;  // diagonal excluded (d=inf in reference)
            double dx = qxd - (double)sx[c];
            double dy = qyd - (double)sy[c];
            double dz = qzd - (double)sz[c];
            double dd = dx * dx + dy * dy + dz * dz;
            if (dd < md || (dd == md && j < mj)) {
#pragma unroll
                for (int s = 0; s < 16; ++s)
                    if (s == mslot) { ld[s] = dd; li[s] = j; }
                md = -1.0; mj = -1; mslot = 0;
#pragma unroll
                for (int s = 0; s < 16; ++s) {
                    bool g = (ld[s] > md) || (ld[s] == md && li[s] > mj);
                    if (g) { md = ld[s]; mj = li[s]; mslot = s; }
                }
            }
        }
    }

    const int out_base = qi * KNN_K;
    for (int r = 0; r < KNN_K; ++r) {
        double cd = DBL_MAX; int cj = 0x7fffffff; int cs = 0;
#pragma unroll
        for (int s = 0; s < 16; ++s) {
            bool l = (ld[s] < cd) || (ld[s] == cd && li[s] < cj);
            if (l) { cd = ld[s]; cj = li[s]; cs = s; }
        }
        double wd = cd; int wj = cj;
        for (int off = 32; off; off >>= 1) {
            double od = __shfl_xor(wd, off);
            int oj = __shfl_xor(wj, off);
            if (od < wd || (od == wd && oj < wj)) { wd = od; wj = oj; }
        }
        if (cd == wd && cj == wj) {
#pragma unroll
            for (int s = 0; s < 16; ++s)
                if (s == cs) { ld[s] = DBL_MAX; li[s] = 0x7fffffff; }
        }
        if (lane == 0) knn_out[out_base + r] = wj;
    }
}

// ---------------------------------------------------------------------------
// EdgeConv MLP + maxpool: one wave per point (lane = channel 0..63).
// ---------------------------------------------------------------------------
__global__ __launch_bounds__(256) void edgeconv_kernel(
    const float* __restrict__ pts, const int* __restrict__ knn,
    const float* __restrict__ ew1, const float* __restrict__ eb1,
    const float* __restrict__ ew2, const float* __restrict__ eb2,
    float* __restrict__ feats) {
    __shared__ float w1[6 * 64], b1v[64], w2[64 * 64], b2v[64];
    for (int t = threadIdx.x; t < 6 * 64; t += 256) w1[t] = ew1[t];
    for (int t = threadIdx.x; t < 64; t += 256) { b1v[t] = eb1[t]; b2v[t] = eb2[t]; }
    for (int t = threadIdx.x; t < 64 * 64; t += 256) w2[t] = ew2[t];
    __syncthreads();

    const int wave = threadIdx.x >> 6, lane = threadIdx.x & 63;
    const int p = blockIdx.x * 4 + wave;
    const float xi = pts[p * 3], yi = pts[p * 3 + 1], zi = pts[p * 3 + 2];
    float acc = -FLT_MAX;
    for (int k = 0; k < KNN_K; ++k) {
        const int j = knn[p * 16 + k];
        const float xj = pts[j * 3], yj = pts[j * 3 + 1], zj = pts[j * 3 + 2];
        const float f0 = xi, f1 = yi, f2 = zi;
        const float f3 = xj - xi, f4 = yj - yi, f5 = zj - zi;
        float h1 = b1v[lane];
        h1 = fmaf(f0, w1[0 * 64 + lane], h1);
        h1 = fmaf(f1, w1[1 * 64 + lane], h1);
        h1 = fmaf(f2, w1[2 * 64 + lane], h1);
        h1 = fmaf(f3, w1[3 * 64 + lane], h1);
        h1 = fmaf(f4, w1[4 * 64 + lane], h1);
        h1 = fmaf(f5, w1[5 * 64 + lane], h1);
        h1 = fmaxf(h1, 0.0f);
        float h2 = b2v[lane];
        for (int d = 0; d < 64; ++d)
            h2 = fmaf(__shfl(h1, d), w2[d * 64 + lane], h2);
        acc = fmaxf(acc, h2);
    }
    feats[p * 64 + lane] = acc;
}

// ---------------------------------------------------------------------------
// FPS v3: 512 threads (8 waves), P = n/512 points/thread, ALL register arrays
// indexed only from fully-unrolled loops (no scratch spill).
// Hot loop: certified fp32 (direct-form error <= ~6e-7 rel), per-thread top-2,
// wave butterfly, 1 barrier, 8-slot LDS merge. If the global top-2 gap is
// < 3e-6 rel, fp32 cannot certify the fp64 argmax: COOPERATIVE fp64 fallback
// re-evaluates band candidates (LDS list) with the history scan split across
// all 512 threads (~1us per trigger, expected few-% trigger rate).
// ---------------------------------------------------------------------------
template <int P>
__global__ __launch_bounds__(512, 2) void fps_kernel(const float* __restrict__ pts,
                                                     int n_out,
                                                     int* __restrict__ fi) {
    __shared__ float rm1[2][8];
    __shared__ int rg1[2][8];
    __shared__ float rm2[2][8];
    __shared__ int cand_idx[64];
    __shared__ int cand_cnt;
    __shared__ int more_flag;
    __shared__ double red_d[8];
    const int tid = threadIdx.x;
    const int wave = tid >> 6, lane = tid & 63;

    float px[P], py[P], pz[P], c[P];
#pragma unroll
    for (int q = 0; q < P; ++q) {
        const int g = tid + q * FPS_T;
        px[q] = pts[g * 3 + 0];
        py[q] = pts[g * 3 + 1];
        pz[q] = pts[g * 3 + 2];
        c[q] = FLT_MAX;
    }
    float sx = pts[0], sy = pts[1], sz = pts[2];
    if (tid == 0) fi[0] = 0;

    for (int it = 1; it < n_out; ++it) {
        // fused min-update + per-thread top-2 (all register arrays, unrolled)
        float m1 = -1.0f, m2 = -1.0f;
        int g1 = 0x7fffffff;
#pragma unroll
        for (int q = 0; q < P; ++q) {
            float dx = px[q] - sx, dy = py[q] - sy, dz = pz[q] - sz;
            float t = fmaf(dx, dx, fmaf(dy, dy, dz * dz));
            float nc = fminf(c[q], t);
            c[q] = nc;
            bool gt = nc > m1;
            m2 = fmaxf(m2, fminf(nc, m1));
            m1 = fmaxf(m1, nc);
            g1 = gt ? (tid + q * FPS_T) : g1;
        }
        // wave butterfly top-2 merge
        for (int off = 32; off; off >>= 1) {
            float om1 = __shfl_xor(m1, off);
            int og1 = __shfl_xor(g1, off);
            float om2 = __shfl_xor(m2, off);
            bool take = (om1 > m1) || (om1 == m1 && og1 < g1);
            float sml = take ? m1 : om1;
            m2 = fmaxf(fmaxf(m2, om2), sml);
            m1 = take ? om1 : m1;
            g1 = take ? og1 : g1;
        }
        const int par = it & 1;
        if (lane == 0) { rm1[par][wave] = m1; rg1[par][wave] = g1; rm2[par][wave] = m2; }
        __syncthreads();
        float M1 = rm1[par][0], M2 = rm2[par][0];
        int G1 = rg1[par][0];
#pragma unroll
        for (int w = 1; w < 8; ++w) {
            float om1 = rm1[par][w], om2 = rm2[par][w];
            int og1 = rg1[par][w];
            bool take = (om1 > M1) || (om1 == M1 && og1 < G1);
            float sml = take ? M1 : om1;
            M2 = fmaxf(fmaxf(M2, om2), sml);
            M1 = take ? om1 : M1;
            G1 = take ? og1 : G1;
        }
        int winner = G1;
        const float thr = M1 - M1 * CERT_EPS;
        if (M2 >= thr) {
            // ---- cooperative exact fp64 fallback (uniform branch) ----
            unsigned miss = 0;
#pragma unroll
            for (int q = 0; q < P; ++q)
                if (c[q] >= thr) miss |= (1u << q);
            double BD = -1.0;
            int BG = 0x7fffffff;
            for (;;) {
                if (tid == 0) { cand_cnt = 0; more_flag = 0; }
                __syncthreads();
#pragma unroll
                for (int q = 0; q < P; ++q) {
                    if (miss & (1u << q)) {
                        int slot = atomicAdd(&cand_cnt, 1);
                        if (slot < 64) {
                            cand_idx[slot] = tid + q * FPS_T;
                            miss &= ~(1u << q);
                        } else {
                            more_flag = 1;
                        }
                    }
                }
                __syncthreads();
                int ncand = cand_cnt;
                if (ncand > 64) ncand = 64;
                for (int ci = 0; ci < ncand; ++ci) {
                    const int g = cand_idx[ci];
                    const double qx = (double)pts[g * 3 + 0];
                    const double qy = (double)pts[g * 3 + 1];
                    const double qz = (double)pts[g * 3 + 2];
                    double dmin = DBL_MAX;
                    for (int i = tid; i < it; i += FPS_T) {
                        const int h = fi[i];
                        double ddx = qx - (double)pts[h * 3 + 0];
                        double ddy = qy - (double)pts[h * 3 + 1];
                        double ddz = qz - (double)pts[h * 3 + 2];
                        double dd = ddx * ddx + ddy * ddy + ddz * ddz;
                        dmin = (dd < dmin) ? dd : dmin;
                    }
                    for (int off = 32; off; off >>= 1) {
                        double od = __shfl_xor(dmin, off);
                        dmin = (od < dmin) ? od : dmin;
                    }
                    if (lane == 0) red_d[wave] = dmin;
                    __syncthreads();
                    double dall = red_d[0];
#pragma unroll
                    for (int w = 1; w < 8; ++w) dall = (red_d[w] < dall) ? red_d[w] : dall;
                    if (dall > BD || (dall == BD && g < BG)) { BD = dall; BG = g; }
                    __syncthreads();
                }
                int mf = more_flag;
                __syncthreads();
                if (!mf) break;
            }
            winner = BG;
        }
        if (tid == 0) fi[it] = winner;
        winner = __builtin_amdgcn_readfirstlane(winner);
        sx = pts[winner * 3 + 0];
        sy = pts[winner * 3 + 1];
        sz = pts[winner * 3 + 2];
    }
}

// ---------------------------------------------------------------------------
// Gathers: write sampled coords (exact bit copies) + compose original indices.
// ---------------------------------------------------------------------------
__global__ void gather0_kernel(const float* __restrict__ pts,
                               const int* __restrict__ fi0,
                               float* __restrict__ sp0) {
    int t = blockIdx.x * 256 + threadIdx.x;
    if (t >= 4096) return;
    int g = fi0[t];
    sp0[t * 3 + 0] = pts[g * 3 + 0];
    sp0[t * 3 + 1] = pts[g * 3 + 1];
    sp0[t * 3 + 2] = pts[g * 3 + 2];
}

__global__ void gather_next_kernel(const float* __restrict__ pts,
                                   const int* __restrict__ prev_orig,
                                   const int* __restrict__ fi, int S,
                                   float* __restrict__ sp,
                                   int* __restrict__ orig_out) {
    int t = blockIdx.x * 256 + threadIdx.x;
    if (t >= S) return;
    int f = fi[t];
    int g = prev_orig[f];
    orig_out[t] = g;
    sp[t * 3 + 0] = pts[g * 3 + 0];
    sp[t * 3 + 1] = pts[g * 3 + 1];
    sp[t * 3 + 2] = pts[g * 3 + 2];
}

// ---------------------------------------------------------------------------
// Per-scale MLP: lf = relu(sf @ mw1 + mb1) @ mw2 + mb2.
// ---------------------------------------------------------------------------
__global__ __launch_bounds__(256) void mlp_kernel(
    const float* __restrict__ feats, const int* __restrict__ orig,
    const float* __restrict__ mw1, const float* __restrict__ mb1,
    const float* __restrict__ mw2, const float* __restrict__ mb2,
    float* __restrict__ out) {
    __shared__ float sfl[64], h1l[128];
    const int t = threadIdx.x;
    for (int pl = 0; pl < 16; ++pl) {
        const int p = blockIdx.x * 16 + pl;
        const int g = orig[p];
        if (t < 64) sfl[t] = feats[g * 64 + t];
        __syncthreads();
        if (t < 128) {
            float h = mb1[t];
            for (int dd = 0; dd < 64; ++dd)
                h = fmaf(sfl[dd], mw1[dd * 128 + t], h);
            h1l[t] = fmaxf(h, 0.0f);
        }
        __syncthreads();
        float o = mb2[t];
        for (int dd = 0; dd < 128; ++dd)
            o = fmaf(h1l[dd], mw2[dd * 256 + t], o);
        out[p * 256 + t] = o;
        __syncthreads();
    }
}

// ---------------------------------------------------------------------------
extern "C" void kernel_launch(void* const* d_in, const int* in_sizes, int n_in,
                              void* d_out, int out_size, void* d_ws, size_t ws_size,
                              hipStream_t stream) {
    const float* pts = (const float*)d_in[0];
    const float* ew1 = (const float*)d_in[1];
    const float* eb1 = (const float*)d_in[2];
    const float* ew2 = (const float*)d_in[3];
    const float* eb2 = (const float*)d_in[4];
    const float* mw1 = (const float*)d_in[5];  // (3,64,128)
    const float* mb1 = (const float*)d_in[6];  // (3,128)
    const float* mw2 = (const float*)d_in[7];  // (3,128,256)
    const float* mb2 = (const float*)d_in[8];  // (3,256)
    float* out = (float*)d_out;
    char* ws = (char*)d_ws;

    int* knn = (int*)(ws + 0);
    float* feats = (float*)(ws + 1048576);
    int* fi0 = (int*)(ws + 5242880);
    int* fi1 = (int*)(ws + 5259264);
    int* fi2 = (int*)(ws + 5263360);
    int* orig1 = (int*)(ws + 5264384);
    int* orig2 = (int*)(ws + 5268480);

    float* sp0 = out + 0;
    float* lf0 = out + 12288;
    float* sp1 = out + 1060864;
    float* lf1 = out + 1063936;
    float* sp2 = out + 1326080;
    float* lf2 = out + 1326848;

    knn_kernel<<<N_PTS / 4, 256, 0, stream>>>(pts, knn);
    edgeconv_kernel<<<N_PTS / 4, 256, 0, stream>>>(pts, knn, ew1, eb1, ew2, eb2, feats);

    // scale 0: FPS over 16384 -> 4096
    fps_kernel<32><<<1, 512, 0, stream>>>(pts, 4096, fi0);
    gather0_kernel<<<16, 256, 0, stream>>>(pts, fi0, sp0);
    mlp_kernel<<<4096 / 16, 256, 0, stream>>>(feats, fi0, mw1 + 0 * 8192, mb1 + 0 * 128,
                                              mw2 + 0 * 32768, mb2 + 0 * 256, lf0);

    // scale 1: FPS over sp0 (4096) -> 1024
    fps_kernel<8><<<1, 512, 0, stream>>>(sp0, 1024, fi1);
    gather_next_kernel<<<4, 256, 0, stream>>>(pts, fi0, fi1, 1024, sp1, orig1);
    mlp_kernel<<<1024 / 16, 256, 0, stream>>>(feats, orig1, mw1 + 1 * 8192, mb1 + 1 * 128,
                                              mw2 + 1 * 32768, mb2 + 1 * 256, lf1);

    // scale 2: FPS over sp1 (1024) -> 256
    fps_kernel<2><<<1, 512, 0, stream>>>(sp1, 256, fi2);
    gather_next_kernel<<<1, 256, 0, stream>>>(pts, orig1, fi2, 256, sp2, orig2);
    mlp_kernel<<<256 / 16, 256, 0, stream>>>(feats, orig2, mw1 + 2 * 8192, mb1 + 2 * 128,
                                             mw2 + 2 * 32768, mb2 + 2 * 256, lf2);
}

// Round 4
// 12520.822 us; speedup vs baseline: 5.7201x; 1.0283x over previous
//
#include <hip/hip_runtime.h>
#include <cfloat>
#include <cstdint>

#define N_PTS 16384
#define KNN_K 16
#define KNN_TILE 512
#define CERT_EPS 3e-6f

// ---------------------------------------------------------------------------
// KNN: one wave per query point, per-lane top-16 (fp64 exact) + wave merge.
// ---------------------------------------------------------------------------
__global__ __launch_bounds__(256) void knn_kernel(const float* __restrict__ pts,
                                                  int* __restrict__ knn_out) {
    __shared__ float sx[KNN_TILE], sy[KNN_TILE], sz[KNN_TILE];
    const int wave = threadIdx.x >> 6;
    const int lane = threadIdx.x & 63;
    const int qi = blockIdx.x * 4 + wave;
    const double qxd = (double)pts[qi * 3 + 0];
    const double qyd = (double)pts[qi * 3 + 1];
    const double qzd = (double)pts[qi * 3 + 2];

    double ld[16];
    int li[16];
#pragma unroll
    for (int s = 0; s < 16; ++s) { ld[s] = DBL_MAX; li[s] = 0x7fffffff; }
    double md = DBL_MAX; int mj = 0x7fffffff; int mslot = 0;

    for (int t0 = 0; t0 < N_PTS; t0 += KNN_TILE) {
        __syncthreads();
        for (int t = threadIdx.x; t < KNN_TILE; t += 256) {
            sx[t] = pts[(t0 + t) * 3 + 0];
            sy[t] = pts[(t0 + t) * 3 + 1];
            sz[t] = pts[(t0 + t) * 3 + 2];
        }
        __syncthreads();
#pragma unroll
        for (int m = 0; m < KNN_TILE / 64; ++m) {
            const int c = lane + m * 64;
            const int j = t0 + c;
            if (j == qi) continue;  // diagonal excluded (d=inf in reference)
            double dx = qxd - (double)sx[c];
            double dy = qyd - (double)sy[c];
            double dz = qzd - (double)sz[c];
            double dd = dx * dx + dy * dy + dz * dz;
            if (dd < md || (dd == md && j < mj)) {
#pragma unroll
                for (int s = 0; s < 16; ++s)
                    if (s == mslot) { ld[s] = dd; li[s] = j; }
                md = -1.0; mj = -1; mslot = 0;
#pragma unroll
                for (int s = 0; s < 16; ++s) {
                    bool g = (ld[s] > md) || (ld[s] == md && li[s] > mj);
                    if (g) { md = ld[s]; mj = li[s]; mslot = s; }
                }
            }
        }
    }

    const int out_base = qi * KNN_K;
    for (int r = 0; r < KNN_K; ++r) {
        double cd = DBL_MAX; int cj = 0x7fffffff; int cs = 0;
#pragma unroll
        for (int s = 0; s < 16; ++s) {
            bool l = (ld[s] < cd) || (ld[s] == cd && li[s] < cj);
            if (l) { cd = ld[s]; cj = li[s]; cs = s; }
        }
        double wd = cd; int wj = cj;
        for (int off = 32; off; off >>= 1) {
            double od = __shfl_xor(wd, off);
            int oj = __shfl_xor(wj, off);
            if (od < wd || (od == wd && oj < wj)) { wd = od; wj = oj; }
        }
        if (cd == wd && cj == wj) {
#pragma unroll
            for (int s = 0; s < 16; ++s)
                if (s == cs) { ld[s] = DBL_MAX; li[s] = 0x7fffffff; }
        }
        if (lane == 0) knn_out[out_base + r] = wj;
    }
}

// ---------------------------------------------------------------------------
// EdgeConv MLP + maxpool: one wave per point (lane = channel 0..63).
// ---------------------------------------------------------------------------
__global__ __launch_bounds__(256) void edgeconv_kernel(
    const float* __restrict__ pts, const int* __restrict__ knn,
    const float* __restrict__ ew1, const float* __restrict__ eb1,
    const float* __restrict__ ew2, const float* __restrict__ eb2,
    float* __restrict__ feats) {
    __shared__ float w1[6 * 64], b1v[64], w2[64 * 64], b2v[64];
    for (int t = threadIdx.x; t < 6 * 64; t += 256) w1[t] = ew1[t];
    for (int t = threadIdx.x; t < 64; t += 256) { b1v[t] = eb1[t]; b2v[t] = eb2[t]; }
    for (int t = threadIdx.x; t < 64 * 64; t += 256) w2[t] = ew2[t];
    __syncthreads();

    const int wave = threadIdx.x >> 6, lane = threadIdx.x & 63;
    const int p = blockIdx.x * 4 + wave;
    const float xi = pts[p * 3], yi = pts[p * 3 + 1], zi = pts[p * 3 + 2];
    float acc = -FLT_MAX;
    for (int k = 0; k < KNN_K; ++k) {
        const int j = knn[p * 16 + k];
        const float xj = pts[j * 3], yj = pts[j * 3 + 1], zj = pts[j * 3 + 2];
        const float f0 = xi, f1 = yi, f2 = zi;
        const float f3 = xj - xi, f4 = yj - yi, f5 = zj - zi;
        float h1 = b1v[lane];
        h1 = fmaf(f0, w1[0 * 64 + lane], h1);
        h1 = fmaf(f1, w1[1 * 64 + lane], h1);
        h1 = fmaf(f2, w1[2 * 64 + lane], h1);
        h1 = fmaf(f3, w1[3 * 64 + lane], h1);
        h1 = fmaf(f4, w1[4 * 64 + lane], h1);
        h1 = fmaf(f5, w1[5 * 64 + lane], h1);
        h1 = fmaxf(h1, 0.0f);
        float h2 = b2v[lane];
        for (int d = 0; d < 64; ++d)
            h2 = fmaf(__shfl(h1, d), w2[d * 64 + lane], h2);
        acc = fmaxf(acc, h2);
    }
    feats[p * 64 + lane] = acc;
}

// ---------------------------------------------------------------------------
// FPS v4: T threads (T=512 scale0, T=256 small scales), P = n/T pts/thread.
// __launch_bounds__(T,1): VGPR cap >= 256 under either arg-2 interpretation,
// so all register arrays stay resident (R3's cap-128 spill is the bug fixed
// here). Hot loop: certified fp32, per-thread top-2, wave butterfly, ONE
// barrier, NW-slot LDS merge. Cooperative fp64 fallback when the global
// top-2 gap < CERT_EPS rel (rare).
// ---------------------------------------------------------------------------
template <int T, int P>
__global__ __launch_bounds__(T, 1) void fps_kernel(const float* __restrict__ pts,
                                                   int n_out,
                                                   int* __restrict__ fi) {
    constexpr int NW = T / 64;
    __shared__ float rm1[2][NW];
    __shared__ int rg1[2][NW];
    __shared__ float rm2[2][NW];
    __shared__ int cand_idx[64];
    __shared__ int cand_cnt;
    __shared__ int more_flag;
    __shared__ double red_d[NW];
    const int tid = threadIdx.x;
    const int wave = tid >> 6, lane = tid & 63;

    float px[P], py[P], pz[P], c[P];
#pragma unroll
    for (int q = 0; q < P; ++q) {
        const int g = tid + q * T;
        px[q] = pts[g * 3 + 0];
        py[q] = pts[g * 3 + 1];
        pz[q] = pts[g * 3 + 2];
        c[q] = FLT_MAX;
    }
    float sx = pts[0], sy = pts[1], sz = pts[2];
    if (tid == 0) fi[0] = 0;

    for (int it = 1; it < n_out; ++it) {
        // fused min-update + per-thread top-2 (register arrays, fully unrolled)
        float m1 = -1.0f, m2 = -1.0f;
        int g1 = 0x7fffffff;
#pragma unroll
        for (int q = 0; q < P; ++q) {
            float dx = px[q] - sx, dy = py[q] - sy, dz = pz[q] - sz;
            float t = fmaf(dx, dx, fmaf(dy, dy, dz * dz));
            float nc = fminf(c[q], t);
            c[q] = nc;
            bool gt = nc > m1;
            m2 = fmaxf(m2, fminf(nc, m1));
            m1 = fmaxf(m1, nc);
            g1 = gt ? (tid + q * T) : g1;
        }
        // wave butterfly top-2 merge
        for (int off = 32; off; off >>= 1) {
            float om1 = __shfl_xor(m1, off);
            int og1 = __shfl_xor(g1, off);
            float om2 = __shfl_xor(m2, off);
            bool take = (om1 > m1) || (om1 == m1 && og1 < g1);
            float sml = take ? m1 : om1;
            m2 = fmaxf(fmaxf(m2, om2), sml);
            m1 = take ? om1 : m1;
            g1 = take ? og1 : g1;
        }
        const int par = it & 1;
        if (lane == 0) { rm1[par][wave] = m1; rg1[par][wave] = g1; rm2[par][wave] = m2; }
        __syncthreads();
        float M1 = rm1[par][0], M2 = rm2[par][0];
        int G1 = rg1[par][0];
#pragma unroll
        for (int w = 1; w < NW; ++w) {
            float om1 = rm1[par][w], om2 = rm2[par][w];
            int og1 = rg1[par][w];
            bool take = (om1 > M1) || (om1 == M1 && og1 < G1);
            float sml = take ? M1 : om1;
            M2 = fmaxf(fmaxf(M2, om2), sml);
            M1 = take ? om1 : M1;
            G1 = take ? og1 : G1;
        }
        int winner = G1;
        const float thr = M1 - M1 * CERT_EPS;
        if (M2 >= thr) {
            // ---- cooperative exact fp64 fallback (uniform branch) ----
            unsigned miss = 0;
#pragma unroll
            for (int q = 0; q < P; ++q)
                if (c[q] >= thr) miss |= (1u << q);
            double BD = -1.0;
            int BG = 0x7fffffff;
            for (;;) {
                if (tid == 0) { cand_cnt = 0; more_flag = 0; }
                __syncthreads();
#pragma unroll
                for (int q = 0; q < P; ++q) {
                    if (miss & (1u << q)) {
                        int slot = atomicAdd(&cand_cnt, 1);
                        if (slot < 64) {
                            cand_idx[slot] = tid + q * T;
                            miss &= ~(1u << q);
                        } else {
                            more_flag = 1;
                        }
                    }
                }
                __syncthreads();
                int ncand = cand_cnt;
                if (ncand > 64) ncand = 64;
                for (int ci = 0; ci < ncand; ++ci) {
                    const int g = cand_idx[ci];
                    const double qx = (double)pts[g * 3 + 0];
                    const double qy = (double)pts[g * 3 + 1];
                    const double qz = (double)pts[g * 3 + 2];
                    double dmin = DBL_MAX;
                    for (int i = tid; i < it; i += T) {
                        const int h = fi[i];
                        double ddx = qx - (double)pts[h * 3 + 0];
                        double ddy = qy - (double)pts[h * 3 + 1];
                        double ddz = qz - (double)pts[h * 3 + 2];
                        double dd = ddx * ddx + ddy * ddy + ddz * ddz;
                        dmin = (dd < dmin) ? dd : dmin;
                    }
                    for (int off = 32; off; off >>= 1) {
                        double od = __shfl_xor(dmin, off);
                        dmin = (od < dmin) ? od : dmin;
                    }
                    if (lane == 0) red_d[wave] = dmin;
                    __syncthreads();
                    double dall = red_d[0];
#pragma unroll
                    for (int w = 1; w < NW; ++w) dall = (red_d[w] < dall) ? red_d[w] : dall;
                    if (dall > BD || (dall == BD && g < BG)) { BD = dall; BG = g; }
                    __syncthreads();
                }
                int mf = more_flag;
                __syncthreads();
                if (!mf) break;
            }
            winner = BG;
        }
        if (tid == 0) fi[it] = winner;
        winner = __builtin_amdgcn_readfirstlane(winner);
        sx = pts[winner * 3 + 0];
        sy = pts[winner * 3 + 1];
        sz = pts[winner * 3 + 2];
    }
}

// ---------------------------------------------------------------------------
// Gathers: write sampled coords (exact bit copies) + compose original indices.
// ---------------------------------------------------------------------------
__global__ void gather0_kernel(const float* __restrict__ pts,
                               const int* __restrict__ fi0,
                               float* __restrict__ sp0) {
    int t = blockIdx.x * 256 + threadIdx.x;
    if (t >= 4096) return;
    int g = fi0[t];
    sp0[t * 3 + 0] = pts[g * 3 + 0];
    sp0[t * 3 + 1] = pts[g * 3 + 1];
    sp0[t * 3 + 2] = pts[g * 3 + 2];
}

__global__ void gather_next_kernel(const float* __restrict__ pts,
                                   const int* __restrict__ prev_orig,
                                   const int* __restrict__ fi, int S,
                                   float* __restrict__ sp,
                                   int* __restrict__ orig_out) {
    int t = blockIdx.x * 256 + threadIdx.x;
    if (t >= S) return;
    int f = fi[t];
    int g = prev_orig[f];
    orig_out[t] = g;
    sp[t * 3 + 0] = pts[g * 3 + 0];
    sp[t * 3 + 1] = pts[g * 3 + 1];
    sp[t * 3 + 2] = pts[g * 3 + 2];
}

// ---------------------------------------------------------------------------
// Per-scale MLP: lf = relu(sf @ mw1 + mb1) @ mw2 + mb2.
// ---------------------------------------------------------------------------
__global__ __launch_bounds__(256) void mlp_kernel(
    const float* __restrict__ feats, const int* __restrict__ orig,
    const float* __restrict__ mw1, const float* __restrict__ mb1,
    const float* __restrict__ mw2, const float* __restrict__ mb2,
    float* __restrict__ out) {
    __shared__ float sfl[64], h1l[128];
    const int t = threadIdx.x;
    for (int pl = 0; pl < 16; ++pl) {
        const int p = blockIdx.x * 16 + pl;
        const int g = orig[p];
        if (t < 64) sfl[t] = feats[g * 64 + t];
        __syncthreads();
        if (t < 128) {
            float h = mb1[t];
            for (int dd = 0; dd < 64; ++dd)
                h = fmaf(sfl[dd], mw1[dd * 128 + t], h);
            h1l[t] = fmaxf(h, 0.0f);
        }
        __syncthreads();
        float o = mb2[t];
        for (int dd = 0; dd < 128; ++dd)
            o = fmaf(h1l[dd], mw2[dd * 256 + t], o);
        out[p * 256 + t] = o;
        __syncthreads();
    }
}

// ---------------------------------------------------------------------------
extern "C" void kernel_launch(void* const* d_in, const int* in_sizes, int n_in,
                              void* d_out, int out_size, void* d_ws, size_t ws_size,
                              hipStream_t stream) {
    const float* pts = (const float*)d_in[0];
    const float* ew1 = (const float*)d_in[1];
    const float* eb1 = (const float*)d_in[2];
    const float* ew2 = (const float*)d_in[3];
    const float* eb2 = (const float*)d_in[4];
    const float* mw1 = (const float*)d_in[5];  // (3,64,128)
    const float* mb1 = (const float*)d_in[6];  // (3,128)
    const float* mw2 = (const float*)d_in[7];  // (3,128,256)
    const float* mb2 = (const float*)d_in[8];  // (3,256)
    float* out = (float*)d_out;
    char* ws = (char*)d_ws;

    int* knn = (int*)(ws + 0);
    float* feats = (float*)(ws + 1048576);
    int* fi0 = (int*)(ws + 5242880);
    int* fi1 = (int*)(ws + 5259264);
    int* fi2 = (int*)(ws + 5263360);
    int* orig1 = (int*)(ws + 5264384);
    int* orig2 = (int*)(ws + 5268480);

    float* sp0 = out + 0;
    float* lf0 = out + 12288;
    float* sp1 = out + 1060864;
    float* lf1 = out + 1063936;
    float* sp2 = out + 1326080;
    float* lf2 = out + 1326848;

    knn_kernel<<<N_PTS / 4, 256, 0, stream>>>(pts, knn);
    edgeconv_kernel<<<N_PTS / 4, 256, 0, stream>>>(pts, knn, ew1, eb1, ew2, eb2, feats);

    // scale 0: FPS over 16384 -> 4096
    fps_kernel<512, 32><<<1, 512, 0, stream>>>(pts, 4096, fi0);
    gather0_kernel<<<16, 256, 0, stream>>>(pts, fi0, sp0);
    mlp_kernel<<<4096 / 16, 256, 0, stream>>>(feats, fi0, mw1 + 0 * 8192, mb1 + 0 * 128,
                                              mw2 + 0 * 32768, mb2 + 0 * 256, lf0);

    // scale 1: FPS over sp0 (4096) -> 1024
    fps_kernel<256, 16><<<1, 256, 0, stream>>>(sp0, 1024, fi1);
    gather_next_kernel<<<4, 256, 0, stream>>>(pts, fi0, fi1, 1024, sp1, orig1);
    mlp_kernel<<<1024 / 16, 256, 0, stream>>>(feats, orig1, mw1 + 1 * 8192, mb1 + 1 * 128,
                                              mw2 + 1 * 32768, mb2 + 1 * 256, lf1);

    // scale 2: FPS over sp1 (1024) -> 256
    fps_kernel<256, 4><<<1, 256, 0, stream>>>(sp1, 256, fi2);
    gather_next_kernel<<<1, 256, 0, stream>>>(pts, orig1, fi2, 256, sp2, orig2);
    mlp_kernel<<<256 / 16, 256, 0, stream>>>(feats, orig2, mw1 + 2 * 8192, mb1 + 2 * 128,
                                             mw2 + 2 * 32768, mb2 + 2 * 256, lf2);
}